// Round 4
// baseline (901.954 us; speedup 1.0000x reference)
//
#include <hip/hip_runtime.h>

// BsplineEncoding: N=1M, D=3, K=64, cubic. Row = 195 fp32/point; 780 MB out.
//
// R1-R3 evidence: stores sourced from REGISTERS ran at 5.5 TB/s (R1, even
// with RMW amplification and short blocks); stores sourced from LDS via
// ds_read_b128 ran at 2.9 TB/s (R2 persistent-dbuf R3 identical). The LDS
// read -> lgkmcnt wait -> store dependency starves the write queue.
//
// R4: one pass, zero LDS, zero barriers. Each thread owns one output float4
// (grid-stride, perfectly coalesced). Decode (point, pos-in-row) by constant
// division; compute the B-spline coefficients in registers; select the
// component value with cndmasks; store from registers. ~32 VALU/float
// (~79 us chip-wide) overlaps under the ~124 us HBM write floor.

constexpr int   DIMS      = 3;
constexpr int   K         = 64;
constexpr int   ROW       = DIMS * (1 + K);     // 195 floats per point
constexpr float SCALE     = 30.5f;              // (K-3)/2
constexpr float CLAMP_MAX = 61.0f - 1e-6f;      // K-DEG-EPS
constexpr int   NBLOCKS   = 4096;
constexpr int   NTHREADS  = 256;

__global__ __launch_bounds__(256)
void bspline_kernel(const float* __restrict__ x, float* __restrict__ out,
                    unsigned int total4) {
    const unsigned int stride = NBLOCKS * NTHREADS;
    float4* __restrict__ out4 = reinterpret_cast<float4*>(out);

    for (unsigned int f = blockIdx.x * NTHREADS + threadIdx.x; f < total4;
         f += stride) {
        const unsigned int g0 = f * 4u;          // first float index
        const unsigned int n0 = g0 / 195u;       // magic-mul divide
        const unsigned int r0 = g0 - n0 * 195u;  // pos within row [0,195)

        float comp[4];
#pragma unroll
        for (int k = 0; k < 4; ++k) {
            unsigned int n = n0;
            unsigned int r = r0 + (unsigned int)k;
            if (r >= 195u) { n += 1u; r -= 195u; }          // row crossing
            const unsigned int d = (r >= 130u) ? 2u : ((r >= 65u) ? 1u : 0u);
            const unsigned int j = r - 65u * d;             // 0 = raw x, 1..64 = bins

            // x load: wave's 64 lanes span ~1.3 rows -> <=2 cache lines, L1 hit
            const float xv = x[n * 3u + d];

            float xs = (xv + 1.0f) * SCALE;
            xs = fminf(fmaxf(xs, 0.0f), CLAMP_MAX);
            const int   idx = (int)xs;                      // xs>=0: trunc==floor
            const float u   = xs - (float)idx;
            const float u2  = u * u;
            const float u3  = u2 * u;
            const float om  = 1.0f - u;
            const float c0  = om * om * om * (1.0f / 6.0f);
            const float c1  = (3.0f * u3 - 6.0f * u2 + 4.0f) * (1.0f / 6.0f);
            const float c2  = (-3.0f * u3 + 3.0f * u2 + 3.0f * u + 1.0f) * (1.0f / 6.0f);
            const float c3  = u3 * (1.0f / 6.0f);

            const int tt = (int)j - 1 - idx;                // which coeff slot
            float val = 0.0f;
            val = (tt == 0) ? c0 : val;
            val = (tt == 1) ? c1 : val;
            val = (tt == 2) ? c2 : val;
            val = (tt == 3) ? c3 : val;
            val = (j == 0u) ? xv : val;
            comp[k] = val;
        }
        out4[f] = make_float4(comp[0], comp[1], comp[2], comp[3]);
    }
}

extern "C" void kernel_launch(void* const* d_in, const int* in_sizes, int n_in,
                              void* d_out, int out_size, void* d_ws, size_t ws_size,
                              hipStream_t stream) {
    const float* x  = (const float*)d_in[0];
    float* out      = (float*)d_out;
    const long long n_pts  = in_sizes[0] / DIMS;            // 1,000,000
    const unsigned int total4 =
        (unsigned int)((n_pts * (long long)ROW) / 4);       // 48,750,000
    bspline_kernel<<<dim3(NBLOCKS), dim3(NTHREADS), 0, stream>>>(x, out, total4);
}

// Round 5
// 770.319 us; speedup vs baseline: 1.1709x; 1.1709x over previous
//
#include <hip/hip_runtime.h>

// BsplineEncoding: N=1M, D=3, K=64, cubic. Row = 195 fp32/point; 780 MB out.
//
// Ledger: R1 reg-sourced stores = 5.5 TB/s (but 2.6x traffic); R2/R3 LDS-bulk
// sourced = 2.9 TB/s (ds_read->store starves writes); R4 reg-sourced but
// recompute-per-float = 2.0 TB/s (VALU/VMEM-issue bound: 4 global x loads +
// 4 coeff evals per float4).
//
// R5: per-block param table. Threads 0..191 compute (xv, idx, c0..c3) ONCE
// per (point,dim) into a 6 KB LDS table (32 B records). Store loop: each
// thread owns consecutive float4s; reads 2 param records (handles the rare
// pair-boundary crossing), selects component values with cndmasks, issues a
// fully-coalesced register-sourced global_store_dwordx4. Bulk data never
// passes through LDS; coefficients never recomputed per float.

constexpr int   DIMS        = 3;
constexpr int   K           = 64;
constexpr int   ROW         = DIMS * (1 + K);        // 195
constexpr float SCALE       = 30.5f;                 // (K-3)/2
constexpr float CLAMP_MAX   = 61.0f - 1e-6f;
constexpr int   PTS_PER_BLK = 64;
constexpr int   PAIRS       = PTS_PER_BLK * DIMS;    // 192 (point,dim) pairs
constexpr int   FLT_PER_BLK = PTS_PER_BLK * ROW;     // 12480
constexpr int   V4_PER_BLK  = FLT_PER_BLK / 4;       // 3120

__global__ __launch_bounds__(256)
void bspline_kernel(const float* __restrict__ x, float* __restrict__ out,
                    int n_pairs_total) {
    // 32-B records: [xv, idx_bits, c0, c1, c2, c3, pad, pad].
    // bank(p) = 8p mod 32 -> adjacent pairs hit disjoint bank quads; lanes
    // sharing p broadcast. Record PAIRS is a zeroed sentinel (never selected,
    // but keeps reads in-bounds).
    __shared__ __align__(16) float params[(PAIRS + 1) * 8];
    const int t = threadIdx.x;

    // ---- Phase 1: one parameter eval per (point,dim) ----
    if (t < PAIRS) {
        const int gp = blockIdx.x * PAIRS + t;       // global pair = n*3+d
        float xv = 0.0f;
        if (gp < n_pairs_total) xv = x[gp];          // coalesced
        float xs = (xv + 1.0f) * SCALE;
        xs = fminf(fmaxf(xs, 0.0f), CLAMP_MAX);
        const int   idx = (int)xs;                   // xs>=0: trunc==floor
        const float u   = xs - (float)idx;
        const float u2  = u * u;
        const float u3  = u2 * u;
        const float om  = 1.0f - u;
        float* rec = params + t * 8;
        rec[0] = xv;
        rec[1] = __int_as_float(idx);
        rec[2] = om * om * om * (1.0f / 6.0f);
        rec[3] = (3.0f * u3 - 6.0f * u2 + 4.0f) * (1.0f / 6.0f);
        rec[4] = (-3.0f * u3 + 3.0f * u2 + 3.0f * u + 1.0f) * (1.0f / 6.0f);
        rec[5] = u3 * (1.0f / 6.0f);
    }
    if (t == 255) {                                  // zero the sentinel record
        float* rec = params + PAIRS * 8;
#pragma unroll
        for (int i = 0; i < 8; ++i) rec[i] = 0.0f;
    }
    __syncthreads();

    // ---- Phase 2: coalesced register-sourced store stream ----
    const float4* p4 = reinterpret_cast<const float4*>(params);
    float4* out4 = reinterpret_cast<float4*>(out)
                 + (long long)blockIdx.x * V4_PER_BLK;

    for (int f = t; f < V4_PER_BLK; f += 256) {
        const int pos = f * 4;                       // float offset in block
        const int p   = pos / 65;                    // pair index (magic mul)
        const int j   = pos - p * 65;                // 0..64 within pair
        const int p2  = p + ((j >= 62) ? 1 : 0);     // crossing partner

        const float4 a0 = p4[p * 2];                 // xv, idx, c0, c1
        const float4 a1 = p4[p * 2 + 1];             // c2, c3, -, -
        const float4 b0 = p4[p2 * 2];
        const float4 b1 = p4[p2 * 2 + 1];
        const int ia = __float_as_int(a0.y);
        const int ib = __float_as_int(b0.y);

        float comp[4];
#pragma unroll
        for (int c = 0; c < 4; ++c) {
            const int  o  = j + c;
            const bool cr = (o >= 65);
            const int  oo = cr ? (o - 65) : o;
            const float xv = cr ? b0.x : a0.x;
            const float k0 = cr ? b0.z : a0.z;
            const float k1 = cr ? b0.w : a0.w;
            const float k2 = cr ? b1.x : a1.x;
            const float k3 = cr ? b1.y : a1.y;
            const int  tt = oo - 1 - (cr ? ib : ia);
            float v = 0.0f;
            v = (tt == 0) ? k0 : v;
            v = (tt == 1) ? k1 : v;
            v = (tt == 2) ? k2 : v;
            v = (tt == 3) ? k3 : v;
            v = (oo == 0) ? xv : v;
            comp[c] = v;
        }
        out4[f] = make_float4(comp[0], comp[1], comp[2], comp[3]);
    }
}

extern "C" void kernel_launch(void* const* d_in, const int* in_sizes, int n_in,
                              void* d_out, int out_size, void* d_ws, size_t ws_size,
                              hipStream_t stream) {
    const float* x  = (const float*)d_in[0];
    float* out      = (float*)d_out;
    const int n_pts = in_sizes[0] / DIMS;                         // 1,000,000
    const int nblk  = (n_pts + PTS_PER_BLK - 1) / PTS_PER_BLK;    // 15625
    bspline_kernel<<<dim3(nblk), dim3(256), 0, stream>>>(x, out, n_pts * DIMS);
}

// Round 7
// 768.335 us; speedup vs baseline: 1.1739x; 1.0026x over previous
//
#include <hip/hip_runtime.h>

// BsplineEncoding: N=1M, D=3, K=64, cubic. Row = 195 fp32/point; 780 MB out.
//
// Ledger: R2/R3/R5 — three structurally different kernels (LDS-bulk stream,
// persistent dbuf, LDS param-table + register select) ALL pin at 270 us =
// 2.9 TB/s. Model that fits: cached stores WRITE-ALLOCATE on L2 miss ->
// 780 MB fetch + 780 MB write = 1.56 GB @ 5.8 TB/s = 270 us. The harness
// fillBufferAligned writes 3.12 GB at 6.27 TB/s with FETCH_SIZE ~= 0 — it
// streams with non-temporal stores.
//
// R6b = R5 + non-temporal output stores. __builtin_nontemporal_store needs a
// NATIVE vector type (clang ext_vector_type), not HIP's float4 class — that
// was R6's compile error. Nothing else changed.

typedef float vfloat4 __attribute__((ext_vector_type(4)));

constexpr int   DIMS        = 3;
constexpr int   K           = 64;
constexpr int   ROW         = DIMS * (1 + K);        // 195
constexpr float SCALE       = 30.5f;                 // (K-3)/2
constexpr float CLAMP_MAX   = 61.0f - 1e-6f;
constexpr int   PTS_PER_BLK = 64;
constexpr int   PAIRS       = PTS_PER_BLK * DIMS;    // 192 (point,dim) pairs
constexpr int   FLT_PER_BLK = PTS_PER_BLK * ROW;     // 12480
constexpr int   V4_PER_BLK  = FLT_PER_BLK / 4;       // 3120

__global__ __launch_bounds__(256)
void bspline_kernel(const float* __restrict__ x, float* __restrict__ out,
                    int n_pairs_total) {
    // 32-B records: [xv, idx_bits, c0, c1, c2, c3, pad, pad].
    __shared__ __align__(16) float params[(PAIRS + 1) * 8];
    const int t = threadIdx.x;

    // ---- Phase 1: one parameter eval per (point,dim) ----
    if (t < PAIRS) {
        const int gp = blockIdx.x * PAIRS + t;       // global pair = n*3+d
        float xv = 0.0f;
        if (gp < n_pairs_total) xv = x[gp];          // coalesced
        float xs = (xv + 1.0f) * SCALE;
        xs = fminf(fmaxf(xs, 0.0f), CLAMP_MAX);
        const int   idx = (int)xs;                   // xs>=0: trunc==floor
        const float u   = xs - (float)idx;
        const float u2  = u * u;
        const float u3  = u2 * u;
        const float om  = 1.0f - u;
        float* rec = params + t * 8;
        rec[0] = xv;
        rec[1] = __int_as_float(idx);
        rec[2] = om * om * om * (1.0f / 6.0f);
        rec[3] = (3.0f * u3 - 6.0f * u2 + 4.0f) * (1.0f / 6.0f);
        rec[4] = (-3.0f * u3 + 3.0f * u2 + 3.0f * u + 1.0f) * (1.0f / 6.0f);
        rec[5] = u3 * (1.0f / 6.0f);
    }
    if (t == 255) {                                  // zero the sentinel record
        float* rec = params + PAIRS * 8;
#pragma unroll
        for (int i = 0; i < 8; ++i) rec[i] = 0.0f;
    }
    __syncthreads();

    // ---- Phase 2: coalesced NON-TEMPORAL register-sourced store stream ----
    const float4* p4 = reinterpret_cast<const float4*>(params);
    vfloat4* out4 = reinterpret_cast<vfloat4*>(out)
                  + (long long)blockIdx.x * V4_PER_BLK;

    for (int f = t; f < V4_PER_BLK; f += 256) {
        const int pos = f * 4;                       // float offset in block
        const int p   = pos / 65;                    // pair index (magic mul)
        const int j   = pos - p * 65;                // 0..64 within pair
        const int p2  = p + ((j >= 62) ? 1 : 0);     // crossing partner

        const float4 a0 = p4[p * 2];                 // xv, idx, c0, c1
        const float4 a1 = p4[p * 2 + 1];             // c2, c3, -, -
        const float4 b0 = p4[p2 * 2];
        const float4 b1 = p4[p2 * 2 + 1];
        const int ia = __float_as_int(a0.y);
        const int ib = __float_as_int(b0.y);

        vfloat4 comp;
#pragma unroll
        for (int c = 0; c < 4; ++c) {
            const int  o  = j + c;
            const bool cr = (o >= 65);
            const int  oo = cr ? (o - 65) : o;
            const float xv = cr ? b0.x : a0.x;
            const float k0 = cr ? b0.z : a0.z;
            const float k1 = cr ? b0.w : a0.w;
            const float k2 = cr ? b1.x : a1.x;
            const float k3 = cr ? b1.y : a1.y;
            const int  tt = oo - 1 - (cr ? ib : ia);
            float v = 0.0f;
            v = (tt == 0) ? k0 : v;
            v = (tt == 1) ? k1 : v;
            v = (tt == 2) ? k2 : v;
            v = (tt == 3) ? k3 : v;
            v = (oo == 0) ? xv : v;
            comp[c] = v;
        }
        __builtin_nontemporal_store(comp, &out4[f]);
    }
}

extern "C" void kernel_launch(void* const* d_in, const int* in_sizes, int n_in,
                              void* d_out, int out_size, void* d_ws, size_t ws_size,
                              hipStream_t stream) {
    const float* x  = (const float*)d_in[0];
    float* out      = (float*)d_out;
    const int n_pts = in_sizes[0] / DIMS;                         // 1,000,000
    const int nblk  = (n_pts + PTS_PER_BLK - 1) / PTS_PER_BLK;    // 15625
    bspline_kernel<<<dim3(nblk), dim3(256), 0, stream>>>(x, out, n_pts * DIMS);
}